// Round 3
// baseline (158.074 us; speedup 1.0000x reference)
//
#include <hip/hip_runtime.h>
#include <math.h>

#define HEADS 4
#define CH 64
#define HC 256
#define NEG 0.2f

// caps (expected: deg(N-1)~17, |S1|~18, e1~300; Poisson(16) tails covered)
#define CAP_E2 64      // edges into node N-1 (incl appended self loop)
#define CAP_U  512     // unique S1 nodes
#define H0CAP  2048    // layer-0 edge rows materialized
#define MAXD   64      // per-dst in-degree cap (layer-0 agg)
#define MAXD2  64      // layer-1 edge cap (== CAP_E2)

__device__ __forceinline__ float wave_sum64(float v) {
    #pragma unroll
    for (int off = 32; off; off >>= 1) v += __shfl_down(v, off, 64);
    return v;  // valid in lane 0
}

// counters live at ints[0..15], pos at ints[16..]; whole region is filled
// 0xFF (== -1) by one memset, so counters use the atomicAdd(..)+1 idiom.

// ---- kernel 1: edges (src -> N-1), claim S1 membership ----
__global__ void k_scan_last(const int* __restrict__ ei, int E, int N,
                            int* __restrict__ cnt, int* __restrict__ pos,
                            int* __restrict__ e2_src, int* __restrict__ uniq) {
    int e = blockIdx.x * blockDim.x + threadIdx.x;
    if (e < E) {
        int d = ei[E + e];
        if (d == N - 1) {
            int s = ei[e];
            int j = atomicAdd(&cnt[0], 1) + 1;
            if (j < CAP_E2) e2_src[j] = s;
            if (atomicCAS(&pos[s], -1, -2) == -1) {
                int u = atomicAdd(&cnt[1], 1) + 1;
                if (u < CAP_U) { uniq[u] = s; pos[s] = u; } else pos[s] = 0;
            }
        }
    }
    if (e == 0) {  // appended self loop for node N-1
        int j = atomicAdd(&cnt[0], 1) + 1;
        if (j < CAP_E2) e2_src[j] = N - 1;
        if (atomicCAS(&pos[N - 1], -1, -2) == -1) {
            int u = atomicAdd(&cnt[1], 1) + 1;
            if (u < CAP_U) { uniq[u] = N - 1; pos[N - 1] = u; } else pos[N - 1] = 0;
        }
    }
}

// ---- kernel 2: collect edges with dst in S1 ----
__global__ void k_scan_s1(const int* __restrict__ ei, int E,
                          const int* __restrict__ pos, int* __restrict__ cnt,
                          int* __restrict__ e1s, int* __restrict__ e1d) {
    int e = blockIdx.x * blockDim.x + threadIdx.x;
    if (e >= E) return;
    int d = ei[E + e];
    if (pos[d] >= 0) {
        int j = atomicAdd(&cnt[2], 1) + 1;
        if (j < H0CAP) { e1s[j] = ei[e]; e1d[j] = d; }
    }
}

// ---- kernel 3: blocks [0,H0CAP): h0 row + a_src logit per layer-0 edge;
//                blocks [H0CAP,H0CAP+CAP_U): self row per S1 node
//                (h0self + BOTH a_src and a_dst logits) ----
__global__ __launch_bounds__(256) void k_h0(
    const int* __restrict__ y, const float* __restrict__ emb,
    const float* __restrict__ W0, const float* __restrict__ a_src,
    const float* __restrict__ a_dst, const int* __restrict__ cnt,
    const int* __restrict__ e1s, const int* __restrict__ uniq,
    float* __restrict__ h0, float* __restrict__ als0,
    float* __restrict__ h0self, float* __restrict__ als_self,
    float* __restrict__ ald_self)
{
    __shared__ float xr[CH];
    int b = blockIdx.x;
    int tid = threadIdx.x, wave = tid >> 6, lane = tid & 63;
    int node;
    bool selfrow = (b >= H0CAP);
    if (selfrow) {
        int u = b - H0CAP;
        int ucnt = min(cnt[1] + 1, CAP_U);
        if (u >= ucnt) return;
        node = uniq[u];
    } else {
        int ce1 = min(cnt[2] + 1, H0CAP);
        if (b >= ce1) return;
        node = e1s[b];
    }
    if (tid < CH) xr[tid] = emb[(long)y[node] * CH + tid];
    __syncthreads();
    float acc = 0.f;
    #pragma unroll
    for (int k = 0; k < CH; ++k) acc = fmaf(xr[k], W0[k * HC + tid], acc);
    if (selfrow) {
        int u = b - H0CAP;
        h0self[(long)u * HC + tid] = acc;
        float rs = wave_sum64(acc * a_src[tid]);
        if (lane == 0) als_self[u * HEADS + wave] = rs;
        float rd = wave_sum64(acc * a_dst[tid]);
        if (lane == 0) ald_self[u * HEADS + wave] = rd;
    } else {
        h0[(long)b * HC + tid] = acc;
        float r = wave_sum64(acc * a_src[tid]);
        if (lane == 0) als0[b * HEADS + wave] = r;
    }
}

// ---- kernel 4: per S1 node: attention + aggregate + elu + norm,
//                then fused layer-1 GEMV for e2 edges sourced here ----
__global__ __launch_bounds__(256) void k_agg0(
    const float* __restrict__ a_dst, const float* __restrict__ bias,
    const float* __restrict__ W1, const float* __restrict__ a_src1,
    const int* __restrict__ cnt, const int* __restrict__ uniq,
    const int* __restrict__ e1d, const int* __restrict__ e2_src,
    const int* __restrict__ pos,
    const float* __restrict__ h0, const float* __restrict__ als0,
    const float* __restrict__ h0self, const float* __restrict__ als_self,
    const float* __restrict__ ald_self,
    float* __restrict__ h1, float* __restrict__ als1)
{
    __shared__ int gidx[MAXD];
    __shared__ int nloc_s;
    __shared__ float earr[MAXD + 1][HEADS];  // [nloc] edges + [last] self
    __shared__ float red[HEADS];
    __shared__ float xsh[HC];

    int ucnt = min(cnt[1] + 1, CAP_U);
    int b = blockIdx.x;
    if (b >= ucnt) return;
    int d = uniq[b];
    int tid = threadIdx.x, wave = tid >> 6, lane = tid & 63;

    if (tid == 0) nloc_s = 0;
    __syncthreads();
    int ce1 = min(cnt[2] + 1, H0CAP);
    for (int i = tid; i < ce1; i += 256)
        if (e1d[i] == d) {
            int s = atomicAdd(&nloc_s, 1);
            if (s < MAXD) gidx[s] = i;
        }
    __syncthreads();
    int nloc = min(nloc_s, MAXD);

    // logits: edges then self; al_dst precomputed in k_h0
    for (int idx = tid; idx < (nloc + 1) * HEADS; idx += 256) {
        int j = idx >> 2, h = idx & 3;
        float asv = (j < nloc) ? als0[gidx[j] * HEADS + h] : als_self[b * HEADS + h];
        float e = asv + ald_self[b * HEADS + h];
        earr[j][h] = (e >= 0.f) ? e : NEG * e;
    }
    __syncthreads();
    if (tid < HEADS) {
        float m = -1e30f;
        for (int j = 0; j <= nloc; ++j) m = fmaxf(m, earr[j][tid]);
        float den = 0.f;
        for (int j = 0; j <= nloc; ++j) { float w = expf(earr[j][tid] - m); earr[j][tid] = w; den += w; }
        float inv = 1.f / (den + 1e-16f);
        for (int j = 0; j <= nloc; ++j) earr[j][tid] *= inv;
    }
    __syncthreads();
    float acc = 0.f;
    for (int j = 0; j < nloc; ++j)
        acc = fmaf(earr[j][wave], h0[(long)gidx[j] * HC + tid], acc);
    acc = fmaf(earr[nloc][wave], h0self[(long)b * HC + tid], acc);
    float o = acc + bias[tid];
    o = (o > 0.f) ? o : expm1f(o);
    float ss = wave_sum64(o * o);
    if (lane == 0) red[wave] = ss;
    __syncthreads();
    float nrm = sqrtf(red[0] + red[1] + red[2] + red[3]);
    xsh[tid] = o / fmaxf(nrm, 1e-12f);
    __syncthreads();

    // fused layer-1: h1 rows for e2 edges whose src maps to this block
    int ne = min(cnt[0] + 1, CAP_E2);
    for (int j = 0; j < ne; ++j) {
        if (pos[e2_src[j]] != b) continue;  // wave-uniform
        float a1 = 0.f;
        #pragma unroll 16
        for (int k = 0; k < HC; ++k) a1 = fmaf(xsh[k], W1[k * HC + tid], a1);
        h1[j * HC + tid] = a1;
        float r = wave_sum64(a1 * a_src1[tid]);
        if (lane == 0) als1[j * HEADS + wave] = r;
    }
}

// ---- kernel 5: attention at N-1 + ctx MLP (hidden = relu(ctx@pw1+pb1)) ----
__global__ __launch_bounds__(256) void k_final(
    const float* __restrict__ a_dst, const float* __restrict__ bias,
    const float* __restrict__ pw1, const float* __restrict__ pb1,
    const int* __restrict__ cnt, const int* __restrict__ e2_src,
    const float* __restrict__ h1, const float* __restrict__ als1,
    float* __restrict__ hidden, int N)
{
    __shared__ float al_d_sh[HEADS], red[HEADS];
    __shared__ float earr[MAXD2][HEADS];
    __shared__ float ctx_sh[HC];
    __shared__ float part[HEADS][CH];
    __shared__ int jself_s;

    int tid = threadIdx.x, wave = tid >> 6, lane = tid & 63;
    int ne = min(cnt[0] + 1, CAP_E2);
    if (tid == 0) {
        jself_s = 0;
        for (int j = 0; j < ne; ++j) if (e2_src[j] == N - 1) { jself_s = j; break; }
    }
    __syncthreads();
    int jself = jself_s;
    {
        float r = wave_sum64(h1[jself * HC + tid] * a_dst[tid]);
        if (lane == 0) al_d_sh[wave] = r;
    }
    __syncthreads();
    for (int idx = tid; idx < ne * HEADS; idx += 256) {
        int j = idx >> 2, h = idx & 3;
        float e = als1[j * HEADS + h] + al_d_sh[h];
        earr[j][h] = (e >= 0.f) ? e : NEG * e;
    }
    __syncthreads();
    if (tid < HEADS) {
        float m = -1e30f;
        for (int j = 0; j < ne; ++j) m = fmaxf(m, earr[j][tid]);
        float den = 0.f;
        for (int j = 0; j < ne; ++j) { float w = expf(earr[j][tid] - m); earr[j][tid] = w; den += w; }
        float inv = 1.f / (den + 1e-16f);
        for (int j = 0; j < ne; ++j) earr[j][tid] *= inv;
    }
    __syncthreads();
    float acc = 0.f;
    for (int j = 0; j < ne; ++j)
        acc = fmaf(earr[j][wave], h1[j * HC + tid], acc);
    float o = acc + bias[tid];
    o = (o > 0.f) ? o : expm1f(o);
    float ss = wave_sum64(o * o);
    if (lane == 0) red[wave] = ss;
    __syncthreads();
    float nrm = sqrtf(red[0] + red[1] + red[2] + red[3]);
    ctx_sh[tid] = o / fmaxf(nrm, 1e-12f);
    __syncthreads();

    // hidden = relu(ctx @ pw1 + pb1); split K across the 4 waves
    int col = tid & 63;
    float hv = 0.f;
    #pragma unroll 16
    for (int k = wave * 64; k < wave * 64 + 64; ++k)
        hv = fmaf(ctx_sh[k], pw1[k * CH + col], hv);
    part[wave][col] = hv;
    __syncthreads();
    if (tid < CH) {
        float v = part[0][tid] + part[1][tid] + part[2][tid] + part[3][tid] + pb1[tid];
        hidden[tid] = fmaxf(v, 0.f);
    }
}

// ---- kernel 6: out = hidden @ pw2 + pb2 (64-thr blocks for CU spread) ----
__global__ __launch_bounds__(64) void k_out(
    const float* __restrict__ hidden, const float* __restrict__ pw2,
    const float* __restrict__ pb2, float* __restrict__ out, int V)
{
    __shared__ float h_sh[CH];
    int tid = threadIdx.x;
    h_sh[tid] = hidden[tid];
    __syncthreads();
    int v0 = (blockIdx.x * 64 + tid) * 4;
    if (v0 >= V) return;
    float4 acc = *(const float4*)(pb2 + v0);
    #pragma unroll 8
    for (int k = 0; k < CH; ++k) {
        float hk = h_sh[k];
        float4 w = *(const float4*)(pw2 + (size_t)k * V + v0);
        acc.x = fmaf(hk, w.x, acc.x);
        acc.y = fmaf(hk, w.y, acc.y);
        acc.z = fmaf(hk, w.z, acc.z);
        acc.w = fmaf(hk, w.w, acc.w);
    }
    *(float4*)(out + v0) = acc;
}

extern "C" void kernel_launch(void* const* d_in, const int* in_sizes, int n_in,
                              void* d_out, int out_size, void* d_ws, size_t ws_size,
                              hipStream_t stream) {
    const int*   y      = (const int*)d_in[0];
    const int*   ei     = (const int*)d_in[1];
    const float* emb    = (const float*)d_in[2];
    const float* W0     = (const float*)d_in[3];
    const float* a_src0 = (const float*)d_in[4];
    const float* a_dst0 = (const float*)d_in[5];
    const float* b0     = (const float*)d_in[6];
    const float* W1     = (const float*)d_in[7];
    const float* a_src1 = (const float*)d_in[8];
    const float* a_dst1 = (const float*)d_in[9];
    const float* b1     = (const float*)d_in[10];
    const float* pw1    = (const float*)d_in[11];
    const float* pb1    = (const float*)d_in[12];
    const float* pw2    = (const float*)d_in[13];
    const float* pb2    = (const float*)d_in[14];
    int N = in_sizes[0];
    int E = in_sizes[1] / 2;
    int V = in_sizes[14];
    float* out = (float*)d_out;

    char* p = (char*)d_ws;
    auto alloc = [&](size_t bytes) {
        char* r = p;
        p += (bytes + 255) & ~(size_t)255;
        return r;
    };
    // one 0xFF-filled region: counters + pos map
    int*   ints    = (int*)alloc((size_t)(16 + N) * sizeof(int));
    int*   cnt     = ints;        // [0]=e2 [1]=ucnt [2]=e1 (all start at -1)
    int*   pos     = ints + 16;
    float* hidden  = (float*)alloc(CH * sizeof(float));
    int*   e2      = (int*)alloc(CAP_E2 * sizeof(int));
    int*   uniq    = (int*)alloc(CAP_U * sizeof(int));
    int*   e1s     = (int*)alloc(H0CAP * sizeof(int));
    int*   e1d     = (int*)alloc(H0CAP * sizeof(int));
    float* als0    = (float*)alloc((size_t)H0CAP * HEADS * sizeof(float));
    float* alss    = (float*)alloc((size_t)CAP_U * HEADS * sizeof(float));
    float* alds    = (float*)alloc((size_t)CAP_U * HEADS * sizeof(float));
    float* als1    = (float*)alloc((size_t)CAP_E2 * HEADS * sizeof(float));
    float* h0      = (float*)alloc((size_t)H0CAP * HC * sizeof(float));
    float* h0self  = (float*)alloc((size_t)CAP_U * HC * sizeof(float));
    float* h1      = (float*)alloc((size_t)CAP_E2 * HC * sizeof(float));

    hipMemsetAsync(ints, 0xFF, (size_t)(16 + N) * sizeof(int), stream);

    int blocksE = (E + 255) / 256;
    k_scan_last<<<blocksE, 256, 0, stream>>>(ei, E, N, cnt, pos, e2, uniq);
    k_scan_s1<<<blocksE, 256, 0, stream>>>(ei, E, pos, cnt, e1s, e1d);
    k_h0<<<H0CAP + CAP_U, 256, 0, stream>>>(y, emb, W0, a_src0, a_dst0,
                                            cnt, e1s, uniq,
                                            h0, als0, h0self, alss, alds);
    k_agg0<<<CAP_U, 256, 0, stream>>>(a_dst0, b0, W1, a_src1, cnt, uniq,
                                      e1d, e2, pos, h0, als0, h0self, alss, alds,
                                      h1, als1);
    k_final<<<1, 256, 0, stream>>>(a_dst1, b1, pw1, pb1, cnt, e2, h1, als1, hidden, N);
    k_out<<<(V + 255) / 256, 64, 0, stream>>>(hidden, pw2, pb2, out, V);
}